// Round 3
// baseline (913.753 us; speedup 1.0000x reference)
//
#include <hip/hip_runtime.h>

#define CCH   640
#define RDIM  128
#define NBS   25
#define CKK   5760
#define SF_B  64000
#define NBLK  512

// ---------------- Workspace layout (float offsets) ----------------
#define OFF_PG0   0        // [25][640] pooled
#define OFF_PGA   16000
#define OFF_PGB   32000
#define OFF_ATA   48000    // [640][9]
#define OFF_ATB   53760
#define OFF_BA    59520    // [16]
#define OFF_BB    59536
#define OFF_SKT   59552    // [2][25][900]
#define OFF_SKS   104552   // [2][25][900]
#define OFF_SKSCT 149552   // [9][25][100]
#define OFF_CKT   172052   // [25][5760]
#define OFF_CKS   316052   // [25][5760]
#define OFF_TASKT 460052   // [9][640][100]  (ends at 1036052)
#define OFF_BAR   2000000  // 6 u32 barrier counters, zeroed by hipMemsetAsync

// Grid barrier: counter per phase, zeroed host-side before each launch.
// Release fence -> device-scope arrive -> poll (RMW-with-0 as device-scope
// load) with backoff -> acquire fence. 512 blocks = 2/CU resident for any
// VGPR count, so co-residency (and thus progress) is guaranteed.
#define GSYNC(id) do {                                                        \
    __syncthreads();                                                          \
    if (t == 0) {                                                             \
        __threadfence();                                                      \
        unsigned prev_ = atomicAdd(&bar[(id)], 1u);                           \
        if (prev_ != (unsigned)(NBLK - 1)) {                                  \
            while (atomicAdd(&bar[(id)], 0u) < (unsigned)NBLK) {              \
                for (volatile int z_ = 0; z_ < 128; ++z_) {}                  \
            }                                                                 \
        }                                                                     \
        __threadfence();                                                      \
    }                                                                         \
    __syncthreads();                                                          \
} while (0)

// P-chain step: Pout[b][o] = dot(Wp[o,:], Pin[b,:]) + bp[o]; one wave per (o,b).
#define P_STEP(Pin, Wp, bp, Pout, WG0, STR) do {                              \
    for (int W_ = (WG0); W_ < 16000; W_ += (STR)) {                           \
        int o_ = W_ / NBS, b_ = W_ % NBS;                                     \
        const float2* w2_ = (const float2*)((Wp) + o_ * CCH);                 \
        const float2* p2_ = (const float2*)((Pin) + b_ * CCH);                \
        float acc_ = 0.f;                                                     \
        for (int s_ = 0; s_ < 5; ++s_) {                                      \
            float2 wv_ = w2_[s_ * 64 + lane];                                 \
            float2 pv_ = p2_[s_ * 64 + lane];                                 \
            acc_ += wv_.x * pv_.x + wv_.y * pv_.y;                            \
        }                                                                     \
        for (int m_ = 32; m_ >= 1; m_ >>= 1) acc_ += __shfl_xor(acc_, m_);    \
        if (lane == 0) (Pout)[b_ * CCH + o_] = acc_ + (bp)[o_];               \
    }                                                                         \
} while (0)

// A-chain step: Aout[c*9+k] = sum_o Ain[o*9+k] * Wa[o*640+c]
#define A_STEP(w, Ain, Wa, Aout) do {                                         \
    int k_ = (w) / 10, ctile_ = (w) % 10;                                     \
    int og_ = t >> 6, cl_ = t & 63;                                           \
    int c_ = ctile_ * 64 + cl_;                                               \
    int o0_ = og_ * 160;                                                      \
    float acc_ = 0.f;                                                         \
    for (int o_ = o0_; o_ < o0_ + 160; ++o_)                                  \
        acc_ += (Ain)[o_ * 9 + k_] * (Wa)[o_ * CCH + c_];                     \
    red[t] = acc_;                                                            \
    __syncthreads();                                                          \
    if (t < 64)                                                               \
        (Aout)[(ctile_ * 64 + t) * 9 + k_] =                                  \
            red[t] + red[64 + t] + red[128 + t] + red[192 + t];               \
} while (0)

// First A-step: Ain row comes from Ws[k,:]
#define A_STEP_FIRST(w, Wa, Aout) do {                                        \
    int k_ = (w) / 10, ctile_ = (w) % 10;                                     \
    int og_ = t >> 6, cl_ = t & 63;                                           \
    int c_ = ctile_ * 64 + cl_;                                               \
    int o0_ = og_ * 160;                                                      \
    const float* ar_ = Ws + k_ * CCH;                                         \
    float acc_ = 0.f;                                                         \
    for (int o_ = o0_; o_ < o0_ + 160; ++o_)                                  \
        acc_ += ar_[o_] * (Wa)[o_ * CCH + c_];                                \
    red[t] = acc_;                                                            \
    __syncthreads();                                                          \
    if (t < 64)                                                               \
        (Aout)[(ctile_ * 64 + t) * 9 + k_] =                                  \
            red[t] + red[64 + t] + red[128 + t] + red[192 + t];               \
} while (0)

// B-chain step: Bout[k] = sum_e Ain[e*9+k]*bvec[e] + Bin[k]
#define B_STEP(kidx, Ain, bvec, Bin, Bout) do {                               \
    float acc_ = 0.f;                                                         \
    for (int s_ = 0; s_ < 10; ++s_) {                                         \
        int e_ = s_ * 64 + lane;                                              \
        acc_ += (Ain)[e_ * 9 + (kidx)] * (bvec)[e_];                          \
    }                                                                         \
    for (int m_ = 32; m_ >= 1; m_ >>= 1) acc_ += __shfl_xor(acc_, m_);        \
    if (lane == 0) (Bout)[(kidx)] = acc_ + (Bin)[(kidx)];                     \
} while (0)

#define B_STEP_FIRST(kidx, bvec, Bout) do {                                   \
    const float* ar_ = Ws + (kidx) * CCH;                                     \
    float acc_ = 0.f;                                                         \
    for (int s_ = 0; s_ < 10; ++s_) {                                         \
        int e_ = s_ * 64 + lane;                                              \
        acc_ += ar_[e_] * (bvec)[e_];                                         \
    }                                                                         \
    for (int m_ = 32; m_ >= 1; m_ >>= 1) acc_ += __shfl_xor(acc_, m_);        \
    if (lane == 0) (Bout)[(kidx)] = acc_ + bs[(kidx)];                        \
} while (0)

__global__ __launch_bounds__(256) void mega_front(
        const float* __restrict__ sf,
        const float* __restrict__ Wc1, const float* __restrict__ bc1,
        const float* __restrict__ Wc2, const float* __restrict__ bc2,
        const float* __restrict__ Wc3, const float* __restrict__ bc3,
        const float* __restrict__ Wc4, const float* __restrict__ bc4,
        const float* __restrict__ W1, const float* __restrict__ b1,
        const float* __restrict__ W2, const float* __restrict__ b2,
        const float* __restrict__ Ws, const float* __restrict__ bs,
        float* __restrict__ ws) {
    __shared__ float red[256];
    const int blk = blockIdx.x, t = threadIdx.x;
    const int lane = t & 63, wib = t >> 6;

    float* Pg0 = ws + OFF_PG0;
    float* Pga = ws + OFF_PGA;
    float* Pgb = ws + OFF_PGB;
    float* ATa = ws + OFF_ATA;
    float* ATb = ws + OFF_ATB;
    float* Ba  = ws + OFF_BA;
    float* Bb  = ws + OFF_BB;
    float* SKT = ws + OFF_SKT;
    float* SKS = ws + OFF_SKS;
    float* SKsT = ws + OFF_SKSCT;
    float* CKT = ws + OFF_CKT;
    float* CKS = ws + OFF_CKS;
    float* TKT = ws + OFF_TASKT;
    unsigned* bar = (unsigned*)(ws + OFF_BAR);

    // ---- Ph0: pool || A1 (Ws*Wc4 -> ATa) || B1 (Ws*bc4+bs -> Ba) ----
    if (blk < 63) {
        int idx = blk * 256 + t;
        if (idx < NBS * CCH) {
            int b = idx / CCH, c = idx % CCH;
            const float4* s4 = (const float4*)(sf + b * SF_B + c * 100);
            float acc = 0.f;
#pragma unroll
            for (int q = 0; q < 25; ++q) {
                float4 v = s4[q];
                acc += (v.x + v.y) + (v.z + v.w);
            }
            Pg0[idx] = acc * 0.01f;
        }
    } else if (blk < 153) {
        A_STEP_FIRST(blk - 63, Wc4, ATa);
    } else if (blk < 156) {
        int kk = (blk - 153) * 4 + wib;
        if (kk < 9) B_STEP_FIRST(kk, bc4, Ba);
    }
    GSYNC(0);

    // ---- Ph1: P1 (Pg0->Pga, Wc1) || A2 (ATa->ATb, Wc3) || B2 (bc3, Ba->Bb) ----
    if (blk < 419) {
        P_STEP(Pg0, Wc1, bc1, Pga, blk * 4 + wib, 1676);
    } else if (blk < 509) {
        A_STEP(blk - 419, ATa, Wc3, ATb);
    } else {
        int kk = (blk - 509) * 4 + wib;
        if (kk < 9) B_STEP(kk, ATa, bc3, Ba, Bb);
    }
    GSYNC(1);

    // ---- Ph2: P2 (Pga->Pgb, Wc2) || A3 (ATb->ATa, Wc2) || B3 (bc2, Bb->Ba) ----
    if (blk < 419) {
        P_STEP(Pga, Wc2, bc2, Pgb, blk * 4 + wib, 1676);
    } else if (blk < 509) {
        A_STEP(blk - 419, ATb, Wc2, ATa);
    } else {
        int kk = (blk - 509) * 4 + wib;
        if (kk < 9) B_STEP(kk, ATb, bc2, Bb, Ba);
    }
    GSYNC(2);

    // ---- Ph3: P3 (Pgb->Pga, Wc3) || A4 (ATa->ATb, Wc1) || B4 (bc1, Ba->Bb) ----
    if (blk < 419) {
        P_STEP(Pgb, Wc3, bc3, Pga, blk * 4 + wib, 1676);
    } else if (blk < 509) {
        A_STEP(blk - 419, ATa, Wc1, ATb);
    } else {
        int kk = (blk - 509) * 4 + wib;
        if (kk < 9) B_STEP(kk, ATa, bc1, Ba, Bb);
    }
    GSYNC(3);

    // ---- Ph4: SK (uses A4T=ATb, beta=Bb) || P4 (Pga->Pgb, Wc4) ----
    if (blk < 176) {
        int sidx = blk * 256 + t;
        if (sidx < 45000) {
            int s = sidx / 22500;
            int rem = sidx % 22500;
            int b = rem / 900;
            int r2 = rem % 900;          // flat f = k*100 + q
            int k = r2 / 100, q = r2 % 100;
            const float* x = sf + b * SF_B + q;
            const float* wsr = Ws + k * CCH;
            int c0 = s * 320;
            float acc0 = 0.f, acc1 = 0.f;
#pragma unroll 8
            for (int c = 0; c < 320; ++c) {
                float xc = x[(c0 + c) * 100];
                acc0 += ATb[(c0 + c) * 9 + k] * xc;
                acc1 += wsr[c0 + c] * xc;
            }
            if (s == 0) { acc0 += Bb[k]; acc1 += bs[k]; }
            int p = r2 / 9, uv = r2 % 9;
            int dst = s * 22500 + b * 900 + uv * 100 + p;
            SKT[dst] = acc0;
            SKS[dst] = acc1;
        }
    } else {
        P_STEP(Pga, Wc4, bc4, Pgb, (blk - 176) * 4 + wib, 1344);
    }
    GSYNC(4);

    // ---- Ph5: h + ck (task from Pgb, instance from Pg0) || sksT combine ----
    if (blk < 450) {
        int b = blk / 18, jc = blk % 18, jb = jc * 320;
        {
            int r = t & 127;
            const float* prow = ((t < 128) ? Pgb : Pg0) + b * CCH;
            float acc = b1[r];
#pragma unroll 8
            for (int c = 0; c < CCH; ++c) acc += prow[c] * W1[c * RDIM + r];
            red[t] = fmaxf(acc, 0.f);
        }
        __syncthreads();
        for (int j = jb + t; j < jb + 320; j += 256) {
            float a0 = b2[j], a1 = b2[j];
#pragma unroll 4
            for (int r = 0; r < RDIM; ++r) {
                float w = W2[r * CKK + j];
                a0 += red[r] * w;
                a1 += red[128 + r] * w;
            }
            CKT[b * CKK + j] = a0;
            CKS[b * CKK + j] = a1;
        }
    } else {
        for (int cidx = (blk - 450) * 256 + t; cidx < 22500; cidx += 62 * 256) {
            int uv = cidx / 2500;
            int r = cidx % 2500;          // b*100+p
            int src = (r / 100) * 900 + uv * 100 + (r % 100);
            SKsT[cidx] = SKS[src] + SKS[22500 + src];
        }
    }
    GSYNC(5);

    // ---- Ph6: task kernel assemble ----
    for (int idx = blk * 256 + t; idx < 576000; idx += NBLK * 256) {
        int uv = idx / 64000;
        int rem = idx % 64000;
        int c = rem / 100, p = rem % 100;
        float acc = 0.f;
#pragma unroll
        for (int b = 0; b < NBS; ++b)
            acc += CKT[b * CKK + c * 9 + uv] *
                   (SKT[b * 900 + uv * 100 + p] + SKT[22500 + b * 900 + uv * 100 + p]);
        TKT[idx] = acc * 0.04f;
    }
}

// Merged involutions, verbatim from the harness-verified round-0 kernel.
__global__ __launch_bounds__(256) void involutions(
        const float* __restrict__ sf, const float* __restrict__ qf,
        const float* __restrict__ taskT, const float* __restrict__ cks,
        const float* __restrict__ sksT, float* __restrict__ out) {
    int idx = blockIdx.x * 256 + threadIdx.x;     // max 6.4M
    bool support = idx < NBS * SF_B;
    int b, c, p;
    const float* x;
    if (support) {
        b = idx / SF_B; int rem = idx % SF_B; c = rem / 100; p = rem % 100;
        x = sf + b * SF_B + c * 100;
    } else {
        int qidx = idx - NBS * SF_B;
        b = qidx / SF_B; int rem = qidx % SF_B; c = rem / 100; p = rem % 100;
        x = qf + b * SF_B + c * 100;
    }
    int i = p / 10, j = p % 10;
    float acc = 0.f;
#pragma unroll
    for (int u = 0; u < 3; ++u) {
        int ii = i + u - 1;
        float mrow = ((unsigned)ii < 10u) ? 1.f : 0.f;
        int ci = min(max(ii, 0), 9);
#pragma unroll
        for (int v = 0; v < 3; ++v) {
            int jj = j + v - 1;
            float m = ((unsigned)jj < 10u) ? mrow : 0.f;
            int cj = min(max(jj, 0), 9);
            float xv = x[ci * 10 + cj] * m;     // clamped addr, masked value
            int uv = u * 3 + v;
            float w = taskT[uv * 64000 + c * 100 + p];
            if (support)
                w *= cks[b * CKK + c * 9 + uv] * sksT[uv * 2500 + b * 100 + p];
            acc += w * xv;
        }
    }
    out[idx] = acc;
}

extern "C" void kernel_launch(void* const* d_in, const int* in_sizes, int n_in,
                              void* d_out, int out_size, void* d_ws, size_t ws_size,
                              hipStream_t stream) {
    const float* sf  = (const float*)d_in[0];
    const float* qf  = (const float*)d_in[1];
    const float* Wc1 = (const float*)d_in[2];
    const float* bc1 = (const float*)d_in[3];
    const float* Wc2 = (const float*)d_in[4];
    const float* bc2 = (const float*)d_in[5];
    const float* Wc3 = (const float*)d_in[6];
    const float* bc3 = (const float*)d_in[7];
    const float* Wc4 = (const float*)d_in[8];
    const float* bc4 = (const float*)d_in[9];
    const float* W1 = (const float*)d_in[10];
    const float* b1 = (const float*)d_in[11];
    const float* W2 = (const float*)d_in[12];
    const float* b2 = (const float*)d_in[13];
    const float* Ws = (const float*)d_in[14];
    const float* bs = (const float*)d_in[15];
    float* out = (float*)d_out;
    float* ws = (float*)d_ws;

    // zero the 6 grid-barrier counters (graph-capture-legal async memset)
    hipMemsetAsync((char*)d_ws + OFF_BAR * sizeof(float), 0, 64, stream);

    mega_front<<<NBLK, 256, 0, stream>>>(sf, Wc1, bc1, Wc2, bc2, Wc3, bc3,
                                         Wc4, bc4, W1, b1, W2, b2, Ws, bs, ws);

    involutions<<<25000, 256, 0, stream>>>(sf, qf, ws + OFF_TASKT, ws + OFF_CKS,
                                           ws + OFF_SKSCT, out);
}

// Round 4
// 518.796 us; speedup vs baseline: 1.7613x; 1.7613x over previous
//
#include <hip/hip_runtime.h>

#define CCH   640
#define RDIM  128
#define NBS   25
#define CKK   5760
#define SF_B  64000
#define NBLK  512

// ---------------- Workspace layout (float offsets) ----------------
#define OFF_PG0   0        // [25][640] pooled
#define OFF_PGA   16000
#define OFF_PGB   32000
#define OFF_ATA   48000    // [640][9]
#define OFF_ATB   53760
#define OFF_BA    59520    // [16]
#define OFF_BB    59536
#define OFF_SKT   59552    // [2][25][900]
#define OFF_SKS   104552   // [2][25][900]
#define OFF_SKSCT 149552   // [9][25][100]
#define OFF_CKT   172052   // [25][5760]
#define OFF_CKS   316052   // [25][5760]
#define OFF_TASKT 460052   // [9][640][100]  (ends at 1036052)
#define OFF_BAR   2000000  // barrier counters, zeroed by hipMemsetAsync

// Grid barrier. R3 post-mortem: polling with atomicAdd(+0) continuously =
// device-scope HBM RMW storm (87 MB FETCH/dispatch, 796 us @ 2.4% VALU).
// Fix: probe rarely — ~2400-cycle dependent-FMA backoff in registers (no
// memory traffic), kept live by an impossible-branch guard the compiler
// can't prove away. 512 blocks = 2/CU resident for any VGPR count.
#define GSYNC(id) do {                                                        \
    __syncthreads();                                                          \
    if (t == 0) {                                                             \
        __threadfence();                                                      \
        unsigned prev_ = atomicAdd(&bar[(id)], 1u);                           \
        if (prev_ != (unsigned)(NBLK - 1)) {                                  \
            float bk_ = (float)(prev_ & 7u);                                  \
            while (atomicAdd(&bar[(id)], 0u) < (unsigned)NBLK) {              \
                for (int z_ = 0; z_ < 600; ++z_)                              \
                    bk_ = fmaf(bk_, 1.0000001f, 1e-7f);                       \
            }                                                                 \
            if (bk_ == 1234.5678f) bar[8] = 9u;  /* never true; keeps bk_ */  \
        }                                                                     \
        __threadfence();                                                      \
    }                                                                         \
    __syncthreads();                                                          \
} while (0)

// P-chain step: Pout[b][o] = dot(Wp[o,:], Pin[b,:]) + bp[o]; one wave per (o,b).
#define P_STEP(Pin, Wp, bp, Pout, WG0, STR) do {                              \
    for (int W_ = (WG0); W_ < 16000; W_ += (STR)) {                           \
        int o_ = W_ / NBS, b_ = W_ % NBS;                                     \
        const float2* w2_ = (const float2*)((Wp) + o_ * CCH);                 \
        const float2* p2_ = (const float2*)((Pin) + b_ * CCH);                \
        float acc_ = 0.f;                                                     \
        for (int s_ = 0; s_ < 5; ++s_) {                                      \
            float2 wv_ = w2_[s_ * 64 + lane];                                 \
            float2 pv_ = p2_[s_ * 64 + lane];                                 \
            acc_ += wv_.x * pv_.x + wv_.y * pv_.y;                            \
        }                                                                     \
        for (int m_ = 32; m_ >= 1; m_ >>= 1) acc_ += __shfl_xor(acc_, m_);    \
        if (lane == 0) (Pout)[b_ * CCH + o_] = acc_ + (bp)[o_];               \
    }                                                                         \
} while (0)

// A-chain step: Aout[c*9+k] = sum_o Ain[o*9+k] * Wa[o*640+c]
#define A_STEP(w, Ain, Wa, Aout) do {                                         \
    int k_ = (w) / 10, ctile_ = (w) % 10;                                     \
    int og_ = t >> 6, cl_ = t & 63;                                           \
    int c_ = ctile_ * 64 + cl_;                                               \
    int o0_ = og_ * 160;                                                      \
    float acc_ = 0.f;                                                         \
    _Pragma("unroll 8")                                                       \
    for (int o_ = o0_; o_ < o0_ + 160; ++o_)                                  \
        acc_ += (Ain)[o_ * 9 + k_] * (Wa)[o_ * CCH + c_];                     \
    red[t] = acc_;                                                            \
    __syncthreads();                                                          \
    if (t < 64)                                                               \
        (Aout)[(ctile_ * 64 + t) * 9 + k_] =                                  \
            red[t] + red[64 + t] + red[128 + t] + red[192 + t];               \
} while (0)

// First A-step: Ain row comes from Ws[k,:]
#define A_STEP_FIRST(w, Wa, Aout) do {                                        \
    int k_ = (w) / 10, ctile_ = (w) % 10;                                     \
    int og_ = t >> 6, cl_ = t & 63;                                           \
    int c_ = ctile_ * 64 + cl_;                                               \
    int o0_ = og_ * 160;                                                      \
    const float* ar_ = Ws + k_ * CCH;                                         \
    float acc_ = 0.f;                                                         \
    _Pragma("unroll 8")                                                       \
    for (int o_ = o0_; o_ < o0_ + 160; ++o_)                                  \
        acc_ += ar_[o_] * (Wa)[o_ * CCH + c_];                                \
    red[t] = acc_;                                                            \
    __syncthreads();                                                          \
    if (t < 64)                                                               \
        (Aout)[(ctile_ * 64 + t) * 9 + k_] =                                  \
            red[t] + red[64 + t] + red[128 + t] + red[192 + t];               \
} while (0)

// B-chain step: Bout[k] = sum_e Ain[e*9+k]*bvec[e] + Bin[k]
#define B_STEP(kidx, Ain, bvec, Bin, Bout) do {                               \
    float acc_ = 0.f;                                                         \
    for (int s_ = 0; s_ < 10; ++s_) {                                         \
        int e_ = s_ * 64 + lane;                                              \
        acc_ += (Ain)[e_ * 9 + (kidx)] * (bvec)[e_];                          \
    }                                                                         \
    for (int m_ = 32; m_ >= 1; m_ >>= 1) acc_ += __shfl_xor(acc_, m_);        \
    if (lane == 0) (Bout)[(kidx)] = acc_ + (Bin)[(kidx)];                     \
} while (0)

#define B_STEP_FIRST(kidx, bvec, Bout) do {                                   \
    const float* ar_ = Ws + (kidx) * CCH;                                     \
    float acc_ = 0.f;                                                         \
    for (int s_ = 0; s_ < 10; ++s_) {                                         \
        int e_ = s_ * 64 + lane;                                              \
        acc_ += ar_[e_] * (bvec)[e_];                                         \
    }                                                                         \
    for (int m_ = 32; m_ >= 1; m_ >>= 1) acc_ += __shfl_xor(acc_, m_);        \
    if (lane == 0) (Bout)[(kidx)] = acc_ + bs[(kidx)];                        \
} while (0)

__global__ __launch_bounds__(256) void mega_front(
        const float* __restrict__ sf,
        const float* __restrict__ Wc1, const float* __restrict__ bc1,
        const float* __restrict__ Wc2, const float* __restrict__ bc2,
        const float* __restrict__ Wc3, const float* __restrict__ bc3,
        const float* __restrict__ Wc4, const float* __restrict__ bc4,
        const float* __restrict__ W1, const float* __restrict__ b1,
        const float* __restrict__ W2, const float* __restrict__ b2,
        const float* __restrict__ Ws, const float* __restrict__ bs,
        float* __restrict__ ws) {
    __shared__ float red[256];
    const int blk = blockIdx.x, t = threadIdx.x;
    const int lane = t & 63, wib = t >> 6;

    float* Pg0 = ws + OFF_PG0;
    float* Pga = ws + OFF_PGA;
    float* Pgb = ws + OFF_PGB;
    float* ATa = ws + OFF_ATA;
    float* ATb = ws + OFF_ATB;
    float* Ba  = ws + OFF_BA;
    float* Bb  = ws + OFF_BB;
    float* SKT = ws + OFF_SKT;
    float* SKS = ws + OFF_SKS;
    float* SKsT = ws + OFF_SKSCT;
    float* CKT = ws + OFF_CKT;
    float* CKS = ws + OFF_CKS;
    float* TKT = ws + OFF_TASKT;
    unsigned* bar = (unsigned*)(ws + OFF_BAR);

    // ---- Ph0: pool || A1 (Ws*Wc4 -> ATa) || B1 (Ws*bc4+bs -> Ba) ----
    if (blk < 63) {
        int idx = blk * 256 + t;
        if (idx < NBS * CCH) {
            int b = idx / CCH, c = idx % CCH;
            const float4* s4 = (const float4*)(sf + b * SF_B + c * 100);
            float acc = 0.f;
#pragma unroll
            for (int q = 0; q < 25; ++q) {
                float4 v = s4[q];
                acc += (v.x + v.y) + (v.z + v.w);
            }
            Pg0[idx] = acc * 0.01f;
        }
    } else if (blk < 153) {
        A_STEP_FIRST(blk - 63, Wc4, ATa);
    } else if (blk < 156) {
        int kk = (blk - 153) * 4 + wib;
        if (kk < 9) B_STEP_FIRST(kk, bc4, Ba);
    }
    GSYNC(0);

    // ---- Ph1: P1 (Pg0->Pga, Wc1) || A2 (ATa->ATb, Wc3) || B2 (bc3, Ba->Bb) ----
    if (blk < 419) {
        P_STEP(Pg0, Wc1, bc1, Pga, blk * 4 + wib, 1676);
    } else if (blk < 509) {
        A_STEP(blk - 419, ATa, Wc3, ATb);
    } else {
        int kk = (blk - 509) * 4 + wib;
        if (kk < 9) B_STEP(kk, ATa, bc3, Ba, Bb);
    }
    GSYNC(1);

    // ---- Ph2: P2 (Pga->Pgb, Wc2) || A3 (ATb->ATa, Wc2) || B3 (bc2, Bb->Ba) ----
    if (blk < 419) {
        P_STEP(Pga, Wc2, bc2, Pgb, blk * 4 + wib, 1676);
    } else if (blk < 509) {
        A_STEP(blk - 419, ATb, Wc2, ATa);
    } else {
        int kk = (blk - 509) * 4 + wib;
        if (kk < 9) B_STEP(kk, ATb, bc2, Bb, Ba);
    }
    GSYNC(2);

    // ---- Ph3: P3 (Pgb->Pga, Wc3) || A4 (ATa->ATb, Wc1) || B4 (bc1, Ba->Bb) ----
    if (blk < 419) {
        P_STEP(Pgb, Wc3, bc3, Pga, blk * 4 + wib, 1676);
    } else if (blk < 509) {
        A_STEP(blk - 419, ATa, Wc1, ATb);
    } else {
        int kk = (blk - 509) * 4 + wib;
        if (kk < 9) B_STEP(kk, ATa, bc1, Ba, Bb);
    }
    GSYNC(3);

    // ---- Ph4: SK (uses A4T=ATb, beta=Bb) || P4 (Pga->Pgb, Wc4) ----
    if (blk < 176) {
        int sidx = blk * 256 + t;
        if (sidx < 45000) {
            int s = sidx / 22500;
            int rem = sidx % 22500;
            int b = rem / 900;
            int r2 = rem % 900;          // flat f = k*100 + q
            int k = r2 / 100, q = r2 % 100;
            const float* x = sf + b * SF_B + q;
            const float* wsr = Ws + k * CCH;
            int c0 = s * 320;
            float acc0 = 0.f, acc1 = 0.f;
#pragma unroll 8
            for (int c = 0; c < 320; ++c) {
                float xc = x[(c0 + c) * 100];
                acc0 += ATb[(c0 + c) * 9 + k] * xc;
                acc1 += wsr[c0 + c] * xc;
            }
            if (s == 0) { acc0 += Bb[k]; acc1 += bs[k]; }
            int p = r2 / 9, uv = r2 % 9;
            int dst = s * 22500 + b * 900 + uv * 100 + p;
            SKT[dst] = acc0;
            SKS[dst] = acc1;
        }
    } else {
        P_STEP(Pga, Wc4, bc4, Pgb, (blk - 176) * 4 + wib, 1344);
    }
    GSYNC(4);

    // ---- Ph5: h + ck (task from Pgb, instance from Pg0) || sksT combine ----
    if (blk < 450) {
        int b = blk / 18, jc = blk % 18, jb = jc * 320;
        {
            int r = t & 127;
            const float* prow = ((t < 128) ? Pgb : Pg0) + b * CCH;
            float acc = b1[r];
#pragma unroll 8
            for (int c = 0; c < CCH; ++c) acc += prow[c] * W1[c * RDIM + r];
            red[t] = fmaxf(acc, 0.f);
        }
        __syncthreads();
        for (int j = jb + t; j < jb + 320; j += 256) {
            float a0 = b2[j], a1 = b2[j];
#pragma unroll 4
            for (int r = 0; r < RDIM; ++r) {
                float w = W2[r * CKK + j];
                a0 += red[r] * w;
                a1 += red[128 + r] * w;
            }
            CKT[b * CKK + j] = a0;
            CKS[b * CKK + j] = a1;
        }
    } else {
        for (int cidx = (blk - 450) * 256 + t; cidx < 22500; cidx += 62 * 256) {
            int uv = cidx / 2500;
            int r = cidx % 2500;          // b*100+p
            int src = (r / 100) * 900 + uv * 100 + (r % 100);
            SKsT[cidx] = SKS[src] + SKS[22500 + src];
        }
    }
    GSYNC(5);

    // ---- Ph6: task kernel assemble ----
    for (int idx = blk * 256 + t; idx < 576000; idx += NBLK * 256) {
        int uv = idx / 64000;
        int rem = idx % 64000;
        int c = rem / 100, p = rem % 100;
        float acc = 0.f;
#pragma unroll
        for (int b = 0; b < NBS; ++b)
            acc += CKT[b * CKK + c * 9 + uv] *
                   (SKT[b * 900 + uv * 100 + p] + SKT[22500 + b * 900 + uv * 100 + p]);
        TKT[idx] = acc * 0.04f;
    }
}

// Merged involutions, verbatim from the harness-verified round-0 kernel.
__global__ __launch_bounds__(256) void involutions(
        const float* __restrict__ sf, const float* __restrict__ qf,
        const float* __restrict__ taskT, const float* __restrict__ cks,
        const float* __restrict__ sksT, float* __restrict__ out) {
    int idx = blockIdx.x * 256 + threadIdx.x;     // max 6.4M
    bool support = idx < NBS * SF_B;
    int b, c, p;
    const float* x;
    if (support) {
        b = idx / SF_B; int rem = idx % SF_B; c = rem / 100; p = rem % 100;
        x = sf + b * SF_B + c * 100;
    } else {
        int qidx = idx - NBS * SF_B;
        b = qidx / SF_B; int rem = qidx % SF_B; c = rem / 100; p = rem % 100;
        x = qf + b * SF_B + c * 100;
    }
    int i = p / 10, j = p % 10;
    float acc = 0.f;
#pragma unroll
    for (int u = 0; u < 3; ++u) {
        int ii = i + u - 1;
        float mrow = ((unsigned)ii < 10u) ? 1.f : 0.f;
        int ci = min(max(ii, 0), 9);
#pragma unroll
        for (int v = 0; v < 3; ++v) {
            int jj = j + v - 1;
            float m = ((unsigned)jj < 10u) ? mrow : 0.f;
            int cj = min(max(jj, 0), 9);
            float xv = x[ci * 10 + cj] * m;     // clamped addr, masked value
            int uv = u * 3 + v;
            float w = taskT[uv * 64000 + c * 100 + p];
            if (support)
                w *= cks[b * CKK + c * 9 + uv] * sksT[uv * 2500 + b * 100 + p];
            acc += w * xv;
        }
    }
    out[idx] = acc;
}

extern "C" void kernel_launch(void* const* d_in, const int* in_sizes, int n_in,
                              void* d_out, int out_size, void* d_ws, size_t ws_size,
                              hipStream_t stream) {
    const float* sf  = (const float*)d_in[0];
    const float* qf  = (const float*)d_in[1];
    const float* Wc1 = (const float*)d_in[2];
    const float* bc1 = (const float*)d_in[3];
    const float* Wc2 = (const float*)d_in[4];
    const float* bc2 = (const float*)d_in[5];
    const float* Wc3 = (const float*)d_in[6];
    const float* bc3 = (const float*)d_in[7];
    const float* Wc4 = (const float*)d_in[8];
    const float* bc4 = (const float*)d_in[9];
    const float* W1 = (const float*)d_in[10];
    const float* b1 = (const float*)d_in[11];
    const float* W2 = (const float*)d_in[12];
    const float* b2 = (const float*)d_in[13];
    const float* Ws = (const float*)d_in[14];
    const float* bs = (const float*)d_in[15];
    float* out = (float*)d_out;
    float* ws = (float*)d_ws;

    // zero the grid-barrier counters (graph-capture-legal async memset)
    hipMemsetAsync((char*)d_ws + OFF_BAR * sizeof(float), 0, 64, stream);

    mega_front<<<NBLK, 256, 0, stream>>>(sf, Wc1, bc1, Wc2, bc2, Wc3, bc3,
                                         Wc4, bc4, W1, b1, W2, b2, Ws, bs, ws);

    involutions<<<25000, 256, 0, stream>>>(sf, qf, ws + OFF_TASKT, ws + OFF_CKS,
                                           ws + OFF_SKSCT, out);
}

// Round 5
// 398.591 us; speedup vs baseline: 2.2925x; 1.3016x over previous
//
#include <hip/hip_runtime.h>

#define CCH   640
#define RDIM  128
#define NBS   25
#define CKK   5760
#define SF_B  64000
#define NBLK  512

// ---------------- Workspace layout (float offsets) ----------------
#define OFF_PG0   0        // [25][640] pooled
#define OFF_PGA   16000
#define OFF_PGB   32000
#define OFF_ATA   48000    // [640][9]
#define OFF_ATB   53760
#define OFF_BA    59520    // [16]
#define OFF_BB    59536
#define OFF_SKT   59552    // [2][25][900]
#define OFF_SKS   104552   // [2][25][900]
#define OFF_SKSCT 149552   // [9][25][100]
#define OFF_CKT   172052   // [25][5760]
#define OFF_CKS   316052   // [25][5760]
#define OFF_TASKT 460052   // [9][640][100]  (ends at 1036052)
#define OFF_BAR   2000000  // barrier lines, zeroed by hipMemsetAsync (16 KB)

// Hierarchical grid barrier. R4 post-mortem: single-cacheline RMW polling
// from 511 blocks oversubscribes the atomic unit ~6x -> 68 us/barrier.
// Fix: 8 groups x 64 blocks. Arrive on per-group lines (64 RMW each, in
// parallel), cascade through one global line (8 RMW), release via 8
// per-group flag lines; each block polls only its group's flag (64
// pollers/line @ ~1 poll/us = under the ~80/us same-line service rate).
// Every counter/flag sits on its own 64 B line: index = (id*32+slot)*16.
#define GSYNC(id) do {                                                        \
    __syncthreads();                                                          \
    if (t == 0) {                                                             \
        __threadfence();                                                      \
        unsigned* argrp_ = bar + (((id) * 32) + grp) * 16;                    \
        unsigned* arglb_ = bar + (((id) * 32) + 8) * 16;                      \
        unsigned* rel_   = bar + (((id) * 32) + 9 + grp) * 16;                \
        unsigned prev_ = atomicAdd(argrp_, 1u);                               \
        if (prev_ == 63u) {                                                   \
            unsigned gp_ = atomicAdd(arglb_, 1u);                             \
            if (gp_ == 7u) {                                                  \
                for (int g_ = 0; g_ < 8; ++g_)                                \
                    atomicExch(bar + (((id) * 32) + 9 + g_) * 16, 1u);        \
            }                                                                 \
        }                                                                     \
        if (atomicAdd(rel_, 0u) == 0u) {                                      \
            float bk_ = (float)(prev_ & 7u);                                  \
            while (atomicAdd(rel_, 0u) == 0u) {                               \
                for (int z_ = 0; z_ < 600; ++z_)                              \
                    bk_ = fmaf(bk_, 1.0000001f, 1e-7f);                       \
            }                                                                 \
            if (bk_ == 1234.5678f) bar[4095] = 9u;  /* never true */          \
        }                                                                     \
        __threadfence();                                                      \
    }                                                                         \
    __syncthreads();                                                          \
} while (0)

// P-chain step: Pout[b][o] = dot(Wp[o,:], Pin[b,:]) + bp[o]; one wave per (o,b).
#define P_STEP(Pin, Wp, bp, Pout, WG0, STR) do {                              \
    for (int W_ = (WG0); W_ < 16000; W_ += (STR)) {                           \
        int o_ = W_ / NBS, b_ = W_ % NBS;                                     \
        const float2* w2_ = (const float2*)((Wp) + o_ * CCH);                 \
        const float2* p2_ = (const float2*)((Pin) + b_ * CCH);                \
        float acc_ = 0.f;                                                     \
        for (int s_ = 0; s_ < 5; ++s_) {                                      \
            float2 wv_ = w2_[s_ * 64 + lane];                                 \
            float2 pv_ = p2_[s_ * 64 + lane];                                 \
            acc_ += wv_.x * pv_.x + wv_.y * pv_.y;                            \
        }                                                                     \
        for (int m_ = 32; m_ >= 1; m_ >>= 1) acc_ += __shfl_xor(acc_, m_);    \
        if (lane == 0) (Pout)[b_ * CCH + o_] = acc_ + (bp)[o_];               \
    }                                                                         \
} while (0)

// A-chain step: Aout[c*9+k] = sum_o Ain[o*9+k] * Wa[o*640+c]
#define A_STEP(w, Ain, Wa, Aout) do {                                         \
    int k_ = (w) / 10, ctile_ = (w) % 10;                                     \
    int og_ = t >> 6, cl_ = t & 63;                                           \
    int c_ = ctile_ * 64 + cl_;                                               \
    int o0_ = og_ * 160;                                                      \
    float acc_ = 0.f;                                                         \
    _Pragma("unroll 8")                                                       \
    for (int o_ = o0_; o_ < o0_ + 160; ++o_)                                  \
        acc_ += (Ain)[o_ * 9 + k_] * (Wa)[o_ * CCH + c_];                     \
    red[t] = acc_;                                                            \
    __syncthreads();                                                          \
    if (t < 64)                                                               \
        (Aout)[(ctile_ * 64 + t) * 9 + k_] =                                  \
            red[t] + red[64 + t] + red[128 + t] + red[192 + t];               \
} while (0)

// First A-step: Ain row comes from Ws[k,:]
#define A_STEP_FIRST(w, Wa, Aout) do {                                        \
    int k_ = (w) / 10, ctile_ = (w) % 10;                                     \
    int og_ = t >> 6, cl_ = t & 63;                                           \
    int c_ = ctile_ * 64 + cl_;                                               \
    int o0_ = og_ * 160;                                                      \
    const float* ar_ = Ws + k_ * CCH;                                         \
    float acc_ = 0.f;                                                         \
    _Pragma("unroll 8")                                                       \
    for (int o_ = o0_; o_ < o0_ + 160; ++o_)                                  \
        acc_ += ar_[o_] * (Wa)[o_ * CCH + c_];                                \
    red[t] = acc_;                                                            \
    __syncthreads();                                                          \
    if (t < 64)                                                               \
        (Aout)[(ctile_ * 64 + t) * 9 + k_] =                                  \
            red[t] + red[64 + t] + red[128 + t] + red[192 + t];               \
} while (0)

// B-chain step: Bout[k] = sum_e Ain[e*9+k]*bvec[e] + Bin[k]
#define B_STEP(kidx, Ain, bvec, Bin, Bout) do {                               \
    float acc_ = 0.f;                                                         \
    for (int s_ = 0; s_ < 10; ++s_) {                                         \
        int e_ = s_ * 64 + lane;                                              \
        acc_ += (Ain)[e_ * 9 + (kidx)] * (bvec)[e_];                          \
    }                                                                         \
    for (int m_ = 32; m_ >= 1; m_ >>= 1) acc_ += __shfl_xor(acc_, m_);        \
    if (lane == 0) (Bout)[(kidx)] = acc_ + (Bin)[(kidx)];                     \
} while (0)

#define B_STEP_FIRST(kidx, bvec, Bout) do {                                   \
    const float* ar_ = Ws + (kidx) * CCH;                                     \
    float acc_ = 0.f;                                                         \
    for (int s_ = 0; s_ < 10; ++s_) {                                         \
        int e_ = s_ * 64 + lane;                                              \
        acc_ += ar_[e_] * (bvec)[e_];                                         \
    }                                                                         \
    for (int m_ = 32; m_ >= 1; m_ >>= 1) acc_ += __shfl_xor(acc_, m_);        \
    if (lane == 0) (Bout)[(kidx)] = acc_ + bs[(kidx)];                        \
} while (0)

__global__ __launch_bounds__(256) void mega_front(
        const float* __restrict__ sf,
        const float* __restrict__ Wc1, const float* __restrict__ bc1,
        const float* __restrict__ Wc2, const float* __restrict__ bc2,
        const float* __restrict__ Wc3, const float* __restrict__ bc3,
        const float* __restrict__ Wc4, const float* __restrict__ bc4,
        const float* __restrict__ W1, const float* __restrict__ b1,
        const float* __restrict__ W2, const float* __restrict__ b2,
        const float* __restrict__ Ws, const float* __restrict__ bs,
        float* __restrict__ ws) {
    __shared__ float red[256];
    const int blk = blockIdx.x, t = threadIdx.x;
    const int lane = t & 63, wib = t >> 6;
    const int grp = blk >> 6;                 // 8 barrier groups of 64 blocks

    float* Pg0 = ws + OFF_PG0;
    float* Pga = ws + OFF_PGA;
    float* Pgb = ws + OFF_PGB;
    float* ATa = ws + OFF_ATA;
    float* ATb = ws + OFF_ATB;
    float* Ba  = ws + OFF_BA;
    float* Bb  = ws + OFF_BB;
    float* SKT = ws + OFF_SKT;
    float* SKS = ws + OFF_SKS;
    float* SKsT = ws + OFF_SKSCT;
    float* CKT = ws + OFF_CKT;
    float* CKS = ws + OFF_CKS;
    float* TKT = ws + OFF_TASKT;
    unsigned* bar = (unsigned*)(ws + OFF_BAR);

    // ---- Ph0: pool || A1 (Ws*Wc4 -> ATa) || B1 (Ws*bc4+bs -> Ba) ----
    if (blk < 63) {
        int idx = blk * 256 + t;
        if (idx < NBS * CCH) {
            int b = idx / CCH, c = idx % CCH;
            const float4* s4 = (const float4*)(sf + b * SF_B + c * 100);
            float acc = 0.f;
#pragma unroll
            for (int q = 0; q < 25; ++q) {
                float4 v = s4[q];
                acc += (v.x + v.y) + (v.z + v.w);
            }
            Pg0[idx] = acc * 0.01f;
        }
    } else if (blk < 153) {
        A_STEP_FIRST(blk - 63, Wc4, ATa);
    } else if (blk < 156) {
        int kk = (blk - 153) * 4 + wib;
        if (kk < 9) B_STEP_FIRST(kk, bc4, Ba);
    }
    GSYNC(0);

    // ---- Ph1: P1 (Pg0->Pga, Wc1) || A2 (ATa->ATb, Wc3) || B2 (bc3, Ba->Bb) ----
    if (blk < 419) {
        P_STEP(Pg0, Wc1, bc1, Pga, blk * 4 + wib, 1676);
    } else if (blk < 509) {
        A_STEP(blk - 419, ATa, Wc3, ATb);
    } else {
        int kk = (blk - 509) * 4 + wib;
        if (kk < 9) B_STEP(kk, ATa, bc3, Ba, Bb);
    }
    GSYNC(1);

    // ---- Ph2: P2 (Pga->Pgb, Wc2) || A3 (ATb->ATa, Wc2) || B3 (bc2, Bb->Ba) ----
    if (blk < 419) {
        P_STEP(Pga, Wc2, bc2, Pgb, blk * 4 + wib, 1676);
    } else if (blk < 509) {
        A_STEP(blk - 419, ATb, Wc2, ATa);
    } else {
        int kk = (blk - 509) * 4 + wib;
        if (kk < 9) B_STEP(kk, ATb, bc2, Bb, Ba);
    }
    GSYNC(2);

    // ---- Ph3: P3 (Pgb->Pga, Wc3) || A4 (ATa->ATb, Wc1) || B4 (bc1, Ba->Bb) ----
    if (blk < 419) {
        P_STEP(Pgb, Wc3, bc3, Pga, blk * 4 + wib, 1676);
    } else if (blk < 509) {
        A_STEP(blk - 419, ATa, Wc1, ATb);
    } else {
        int kk = (blk - 509) * 4 + wib;
        if (kk < 9) B_STEP(kk, ATa, bc1, Ba, Bb);
    }
    GSYNC(3);

    // ---- Ph4: SK (uses A4T=ATb, beta=Bb) || P4 (Pga->Pgb, Wc4) ----
    if (blk < 176) {
        int sidx = blk * 256 + t;
        if (sidx < 45000) {
            int s = sidx / 22500;
            int rem = sidx % 22500;
            int b = rem / 900;
            int r2 = rem % 900;          // flat f = k*100 + q
            int k = r2 / 100, q = r2 % 100;
            const float* x = sf + b * SF_B + q;
            const float* wsr = Ws + k * CCH;
            int c0 = s * 320;
            float acc0 = 0.f, acc1 = 0.f;
#pragma unroll 8
            for (int c = 0; c < 320; ++c) {
                float xc = x[(c0 + c) * 100];
                acc0 += ATb[(c0 + c) * 9 + k] * xc;
                acc1 += wsr[c0 + c] * xc;
            }
            if (s == 0) { acc0 += Bb[k]; acc1 += bs[k]; }
            int p = r2 / 9, uv = r2 % 9;
            int dst = s * 22500 + b * 900 + uv * 100 + p;
            SKT[dst] = acc0;
            SKS[dst] = acc1;
        }
    } else {
        P_STEP(Pga, Wc4, bc4, Pgb, (blk - 176) * 4 + wib, 1344);
    }
    GSYNC(4);

    // ---- Ph5: h + ck (task from Pgb, instance from Pg0) || sksT combine ----
    if (blk < 450) {
        int b = blk / 18, jc = blk % 18, jb = jc * 320;
        {
            int r = t & 127;
            const float* prow = ((t < 128) ? Pgb : Pg0) + b * CCH;
            float acc = b1[r];
#pragma unroll 8
            for (int c = 0; c < CCH; ++c) acc += prow[c] * W1[c * RDIM + r];
            red[t] = fmaxf(acc, 0.f);
        }
        __syncthreads();
        for (int j = jb + t; j < jb + 320; j += 256) {
            float a0 = b2[j], a1 = b2[j];
#pragma unroll 4
            for (int r = 0; r < RDIM; ++r) {
                float w = W2[r * CKK + j];
                a0 += red[r] * w;
                a1 += red[128 + r] * w;
            }
            CKT[b * CKK + j] = a0;
            CKS[b * CKK + j] = a1;
        }
    } else {
        for (int cidx = (blk - 450) * 256 + t; cidx < 22500; cidx += 62 * 256) {
            int uv = cidx / 2500;
            int r = cidx % 2500;          // b*100+p
            int src = (r / 100) * 900 + uv * 100 + (r % 100);
            SKsT[cidx] = SKS[src] + SKS[22500 + src];
        }
    }
    GSYNC(5);

    // ---- Ph6: task kernel assemble ----
    for (int idx = blk * 256 + t; idx < 576000; idx += NBLK * 256) {
        int uv = idx / 64000;
        int rem = idx % 64000;
        int c = rem / 100, p = rem % 100;
        float acc = 0.f;
#pragma unroll
        for (int b = 0; b < NBS; ++b)
            acc += CKT[b * CKK + c * 9 + uv] *
                   (SKT[b * 900 + uv * 100 + p] + SKT[22500 + b * 900 + uv * 100 + p]);
        TKT[idx] = acc * 0.04f;
    }
}

// Merged involutions, verbatim from the harness-verified round-0 kernel.
__global__ __launch_bounds__(256) void involutions(
        const float* __restrict__ sf, const float* __restrict__ qf,
        const float* __restrict__ taskT, const float* __restrict__ cks,
        const float* __restrict__ sksT, float* __restrict__ out) {
    int idx = blockIdx.x * 256 + threadIdx.x;     // max 6.4M
    bool support = idx < NBS * SF_B;
    int b, c, p;
    const float* x;
    if (support) {
        b = idx / SF_B; int rem = idx % SF_B; c = rem / 100; p = rem % 100;
        x = sf + b * SF_B + c * 100;
    } else {
        int qidx = idx - NBS * SF_B;
        b = qidx / SF_B; int rem = qidx % SF_B; c = rem / 100; p = rem % 100;
        x = qf + b * SF_B + c * 100;
    }
    int i = p / 10, j = p % 10;
    float acc = 0.f;
#pragma unroll
    for (int u = 0; u < 3; ++u) {
        int ii = i + u - 1;
        float mrow = ((unsigned)ii < 10u) ? 1.f : 0.f;
        int ci = min(max(ii, 0), 9);
#pragma unroll
        for (int v = 0; v < 3; ++v) {
            int jj = j + v - 1;
            float m = ((unsigned)jj < 10u) ? mrow : 0.f;
            int cj = min(max(jj, 0), 9);
            float xv = x[ci * 10 + cj] * m;     // clamped addr, masked value
            int uv = u * 3 + v;
            float w = taskT[uv * 64000 + c * 100 + p];
            if (support)
                w *= cks[b * CKK + c * 9 + uv] * sksT[uv * 2500 + b * 100 + p];
            acc += w * xv;
        }
    }
    out[idx] = acc;
}

extern "C" void kernel_launch(void* const* d_in, const int* in_sizes, int n_in,
                              void* d_out, int out_size, void* d_ws, size_t ws_size,
                              hipStream_t stream) {
    const float* sf  = (const float*)d_in[0];
    const float* qf  = (const float*)d_in[1];
    const float* Wc1 = (const float*)d_in[2];
    const float* bc1 = (const float*)d_in[3];
    const float* Wc2 = (const float*)d_in[4];
    const float* bc2 = (const float*)d_in[5];
    const float* Wc3 = (const float*)d_in[6];
    const float* bc3 = (const float*)d_in[7];
    const float* Wc4 = (const float*)d_in[8];
    const float* bc4 = (const float*)d_in[9];
    const float* W1 = (const float*)d_in[10];
    const float* b1 = (const float*)d_in[11];
    const float* W2 = (const float*)d_in[12];
    const float* b2 = (const float*)d_in[13];
    const float* Ws = (const float*)d_in[14];
    const float* bs = (const float*)d_in[15];
    float* out = (float*)d_out;
    float* ws = (float*)d_ws;

    // zero the hierarchical barrier lines (graph-capture-legal async memset)
    hipMemsetAsync((char*)d_ws + OFF_BAR * sizeof(float), 0, 16384, stream);

    mega_front<<<NBLK, 256, 0, stream>>>(sf, Wc1, bc1, Wc2, bc2, Wc3, bc3,
                                         Wc4, bc4, W1, b1, W2, b2, Ws, bs, ws);

    involutions<<<25000, 256, 0, stream>>>(sf, qf, ws + OFF_TASKT, ws + OFF_CKS,
                                           ws + OFF_SKSCT, out);
}

// Round 8
// 390.592 us; speedup vs baseline: 2.3394x; 1.0205x over previous
//
#include <hip/hip_runtime.h>

#define CCH   640
#define RDIM  128
#define NBS   25
#define CKK   5760
#define SF_B  64000
#define NBLK  512

// ---------------- Workspace layout (float offsets) ----------------
#define OFF_PG0   0        // [25][640] pooled
#define OFF_PGA   16000
#define OFF_PGB   32000
#define OFF_ATA   48000    // [640][9]
#define OFF_ATB   53760
#define OFF_BA    59520    // [16]
#define OFF_BB    59536
#define OFF_SKT   59552    // [2][25][900]
#define OFF_SKS   104552   // [2][25][900]
#define OFF_SKSCT 149552   // [9][25][100]
#define OFF_CKT   172052   // [25][5760]
#define OFF_CKS   316052   // [25][5760]
#define OFF_TASKT 460052   // [9][640][100]  (ends at 1036052)
#define OFF_BAR   2000000  // barrier flag lines (6 ids x 2 x 512 x 64B = 384 KB)

#define REL0  3072         // release flags start at line 6*512

// Contention-free grid barrier. R5 post-mortem: same-line device atomics
// serialize ~300-500ns each; 64 participants/line => ~45us/barrier (arrive
// 64x serialized + 64 poll discoveries serialized). Fix: ONE participant
// per cacheline everywhere. Arrive: each block sets its OWN flag line
// (512 parallel lines). Detect: block 0's 256 threads scan all 512 flags
// (independent lines, ~1 memory roundtrip/pass) with LDS-AND reduce.
// Release: block 0's 256 threads set 512 per-block release lines in
// parallel; each block polls only its OWN release line (uncontended).
// Block 0 is trivially resident; no cross-block poll deps => deadlock-free.
#define GSYNC(id) do {                                                        \
    __syncthreads();                                                          \
    if (t == 0) {                                                             \
        __threadfence();                                                      \
        atomicExch(&bar[((id) * 512 + blk) * 16], 1u);                        \
    }                                                                         \
    if (blk == 0) {                                                           \
        for (;;) {                                                            \
            unsigned ok_ =                                                    \
                (atomicAdd(&bar[((id) * 512 + t) * 16], 0u) != 0u) &&         \
                (atomicAdd(&bar[((id) * 512 + t + 256) * 16], 0u) != 0u);     \
            if (t == 0) snotall = 0u;                                         \
            __syncthreads();                                                  \
            if (!ok_) snotall = 1u;                                           \
            __syncthreads();                                                  \
            if (snotall == 0u) break;                                         \
            float bk_ = 1.f;                                                  \
            for (int z_ = 0; z_ < 150; ++z_)                                  \
                bk_ = fmaf(bk_, 1.0000001f, 1e-7f);                           \
            if (bk_ == 1234.5678f) bar[6143 * 16 + 15] = 9u; /* never */      \
            __syncthreads();                                                  \
        }                                                                     \
        __threadfence();                                                      \
        atomicExch(&bar[(REL0 + (id) * 512 + t) * 16], 1u);                   \
        atomicExch(&bar[(REL0 + (id) * 512 + t + 256) * 16], 1u);             \
        __threadfence();                                                      \
    } else if (t == 0) {                                                      \
        unsigned* rel_ = &bar[(REL0 + (id) * 512 + blk) * 16];                \
        if (atomicAdd(rel_, 0u) == 0u) {                                      \
            float bk_ = 1.f;                                                  \
            while (atomicAdd(rel_, 0u) == 0u) {                               \
                for (int z_ = 0; z_ < 200; ++z_)                              \
                    bk_ = fmaf(bk_, 1.0000001f, 1e-7f);                       \
            }                                                                 \
            if (bk_ == 1234.5678f) bar[6143 * 16 + 14] = 9u; /* never */      \
        }                                                                     \
        __threadfence();                                                      \
    }                                                                         \
    __syncthreads();                                                          \
} while (0)

// P-chain step: Pout[b][o] = dot(Wp[o,:], Pin[b,:]) + bp[o]; one wave per (o,b).
#define P_STEP(Pin, Wp, bp, Pout, WG0, STR) do {                              \
    for (int W_ = (WG0); W_ < 16000; W_ += (STR)) {                           \
        int o_ = W_ / NBS, b_ = W_ % NBS;                                     \
        const float2* w2_ = (const float2*)((Wp) + o_ * CCH);                 \
        const float2* p2_ = (const float2*)((Pin) + b_ * CCH);                \
        float acc_ = 0.f;                                                     \
        for (int s_ = 0; s_ < 5; ++s_) {                                      \
            float2 wv_ = w2_[s_ * 64 + lane];                                 \
            float2 pv_ = p2_[s_ * 64 + lane];                                 \
            acc_ += wv_.x * pv_.x + wv_.y * pv_.y;                            \
        }                                                                     \
        for (int m_ = 32; m_ >= 1; m_ >>= 1) acc_ += __shfl_xor(acc_, m_);    \
        if (lane == 0) (Pout)[b_ * CCH + o_] = acc_ + (bp)[o_];               \
    }                                                                         \
} while (0)

// A-chain step: Aout[c*9+k] = sum_o Ain[o*9+k] * Wa[o*640+c]
#define A_STEP(w, Ain, Wa, Aout) do {                                         \
    int k_ = (w) / 10, ctile_ = (w) % 10;                                     \
    int og_ = t >> 6, cl_ = t & 63;                                           \
    int c_ = ctile_ * 64 + cl_;                                               \
    int o0_ = og_ * 160;                                                      \
    float acc_ = 0.f;                                                         \
    _Pragma("unroll 8")                                                       \
    for (int o_ = o0_; o_ < o0_ + 160; ++o_)                                  \
        acc_ += (Ain)[o_ * 9 + k_] * (Wa)[o_ * CCH + c_];                     \
    red[t] = acc_;                                                            \
    __syncthreads();                                                          \
    if (t < 64)                                                               \
        (Aout)[(ctile_ * 64 + t) * 9 + k_] =                                  \
            red[t] + red[64 + t] + red[128 + t] + red[192 + t];               \
} while (0)

// First A-step: Ain row comes from Ws[k,:]
#define A_STEP_FIRST(w, Wa, Aout) do {                                        \
    int k_ = (w) / 10, ctile_ = (w) % 10;                                     \
    int og_ = t >> 6, cl_ = t & 63;                                           \
    int c_ = ctile_ * 64 + cl_;                                               \
    int o0_ = og_ * 160;                                                      \
    const float* ar_ = Ws + k_ * CCH;                                         \
    float acc_ = 0.f;                                                         \
    _Pragma("unroll 8")                                                       \
    for (int o_ = o0_; o_ < o0_ + 160; ++o_)                                  \
        acc_ += ar_[o_] * (Wa)[o_ * CCH + c_];                                \
    red[t] = acc_;                                                            \
    __syncthreads();                                                          \
    if (t < 64)                                                               \
        (Aout)[(ctile_ * 64 + t) * 9 + k_] =                                  \
            red[t] + red[64 + t] + red[128 + t] + red[192 + t];               \
} while (0)

// B-chain step: Bout[k] = sum_e Ain[e*9+k]*bvec[e] + Bin[k]
#define B_STEP(kidx, Ain, bvec, Bin, Bout) do {                               \
    float acc_ = 0.f;                                                         \
    for (int s_ = 0; s_ < 10; ++s_) {                                         \
        int e_ = s_ * 64 + lane;                                              \
        acc_ += (Ain)[e_ * 9 + (kidx)] * (bvec)[e_];                          \
    }                                                                         \
    for (int m_ = 32; m_ >= 1; m_ >>= 1) acc_ += __shfl_xor(acc_, m_);        \
    if (lane == 0) (Bout)[(kidx)] = acc_ + (Bin)[(kidx)];                     \
} while (0)

#define B_STEP_FIRST(kidx, bvec, Bout) do {                                   \
    const float* ar_ = Ws + (kidx) * CCH;                                     \
    float acc_ = 0.f;                                                         \
    for (int s_ = 0; s_ < 10; ++s_) {                                         \
        int e_ = s_ * 64 + lane;                                              \
        acc_ += ar_[e_] * (bvec)[e_];                                         \
    }                                                                         \
    for (int m_ = 32; m_ >= 1; m_ >>= 1) acc_ += __shfl_xor(acc_, m_);        \
    if (lane == 0) (Bout)[(kidx)] = acc_ + bs[(kidx)];                        \
} while (0)

__global__ __launch_bounds__(256) void mega_front(
        const float* __restrict__ sf,
        const float* __restrict__ Wc1, const float* __restrict__ bc1,
        const float* __restrict__ Wc2, const float* __restrict__ bc2,
        const float* __restrict__ Wc3, const float* __restrict__ bc3,
        const float* __restrict__ Wc4, const float* __restrict__ bc4,
        const float* __restrict__ W1, const float* __restrict__ b1,
        const float* __restrict__ W2, const float* __restrict__ b2,
        const float* __restrict__ Ws, const float* __restrict__ bs,
        float* __restrict__ ws) {
    __shared__ float red[256];
    __shared__ unsigned snotall;
    const int blk = blockIdx.x, t = threadIdx.x;
    const int lane = t & 63, wib = t >> 6;

    float* Pg0 = ws + OFF_PG0;
    float* Pga = ws + OFF_PGA;
    float* Pgb = ws + OFF_PGB;
    float* ATa = ws + OFF_ATA;
    float* ATb = ws + OFF_ATB;
    float* Ba  = ws + OFF_BA;
    float* Bb  = ws + OFF_BB;
    float* SKT = ws + OFF_SKT;
    float* SKS = ws + OFF_SKS;
    float* SKsT = ws + OFF_SKSCT;
    float* CKT = ws + OFF_CKT;
    float* CKS = ws + OFF_CKS;
    float* TKT = ws + OFF_TASKT;
    unsigned* bar = (unsigned*)(ws + OFF_BAR);

    // ---- Ph0: pool || A1 (Ws*Wc4 -> ATa) || B1 (Ws*bc4+bs -> Ba) ----
    if (blk < 63) {
        int idx = blk * 256 + t;
        if (idx < NBS * CCH) {
            int b = idx / CCH, c = idx % CCH;
            const float4* s4 = (const float4*)(sf + b * SF_B + c * 100);
            float acc = 0.f;
#pragma unroll
            for (int q = 0; q < 25; ++q) {
                float4 v = s4[q];
                acc += (v.x + v.y) + (v.z + v.w);
            }
            Pg0[idx] = acc * 0.01f;
        }
    } else if (blk < 153) {
        A_STEP_FIRST(blk - 63, Wc4, ATa);
    } else if (blk < 156) {
        int kk = (blk - 153) * 4 + wib;
        if (kk < 9) B_STEP_FIRST(kk, bc4, Ba);
    }
    GSYNC(0);

    // ---- Ph1: P1 (Pg0->Pga, Wc1) || A2 (ATa->ATb, Wc3) || B2 (bc3, Ba->Bb) ----
    if (blk < 419) {
        P_STEP(Pg0, Wc1, bc1, Pga, blk * 4 + wib, 1676);
    } else if (blk < 509) {
        A_STEP(blk - 419, ATa, Wc3, ATb);
    } else {
        int kk = (blk - 509) * 4 + wib;
        if (kk < 9) B_STEP(kk, ATa, bc3, Ba, Bb);
    }
    GSYNC(1);

    // ---- Ph2: P2 (Pga->Pgb, Wc2) || A3 (ATb->ATa, Wc2) || B3 (bc2, Bb->Ba) ----
    if (blk < 419) {
        P_STEP(Pga, Wc2, bc2, Pgb, blk * 4 + wib, 1676);
    } else if (blk < 509) {
        A_STEP(blk - 419, ATb, Wc2, ATa);
    } else {
        int kk = (blk - 509) * 4 + wib;
        if (kk < 9) B_STEP(kk, ATb, bc2, Bb, Ba);
    }
    GSYNC(2);

    // ---- Ph3: P3 (Pgb->Pga, Wc3) || A4 (ATa->ATb, Wc1) || B4 (bc1, Ba->Bb) ----
    if (blk < 419) {
        P_STEP(Pgb, Wc3, bc3, Pga, blk * 4 + wib, 1676);
    } else if (blk < 509) {
        A_STEP(blk - 419, ATa, Wc1, ATb);
    } else {
        int kk = (blk - 509) * 4 + wib;
        if (kk < 9) B_STEP(kk, ATa, bc1, Ba, Bb);
    }
    GSYNC(3);

    // ---- Ph4: SK (uses A4T=ATb, beta=Bb) || P4 (Pga->Pgb, Wc4) ----
    if (blk < 176) {
        int sidx = blk * 256 + t;
        if (sidx < 45000) {
            int s = sidx / 22500;
            int rem = sidx % 22500;
            int b = rem / 900;
            int r2 = rem % 900;          // flat f = k*100 + q
            int k = r2 / 100, q = r2 % 100;
            const float* x = sf + b * SF_B + q;
            const float* wsr = Ws + k * CCH;
            int c0 = s * 320;
            float acc0 = 0.f, acc1 = 0.f;
#pragma unroll 8
            for (int c = 0; c < 320; ++c) {
                float xc = x[(c0 + c) * 100];
                acc0 += ATb[(c0 + c) * 9 + k] * xc;
                acc1 += wsr[c0 + c] * xc;
            }
            if (s == 0) { acc0 += Bb[k]; acc1 += bs[k]; }
            int p = r2 / 9, uv = r2 % 9;
            int dst = s * 22500 + b * 900 + uv * 100 + p;
            SKT[dst] = acc0;
            SKS[dst] = acc1;
        }
    } else {
        P_STEP(Pga, Wc4, bc4, Pgb, (blk - 176) * 4 + wib, 1344);
    }
    GSYNC(4);

    // ---- Ph5: h + ck (task from Pgb, instance from Pg0) || sksT combine ----
    if (blk < 450) {
        int b = blk / 18, jc = blk % 18, jb = jc * 320;
        {
            int r = t & 127;
            const float* prow = ((t < 128) ? Pgb : Pg0) + b * CCH;
            float acc = b1[r];
#pragma unroll 8
            for (int c = 0; c < CCH; ++c) acc += prow[c] * W1[c * RDIM + r];
            red[t] = fmaxf(acc, 0.f);
        }
        __syncthreads();
        for (int j = jb + t; j < jb + 320; j += 256) {
            float a0 = b2[j], a1 = b2[j];
#pragma unroll 4
            for (int r = 0; r < RDIM; ++r) {
                float w = W2[r * CKK + j];
                a0 += red[r] * w;
                a1 += red[128 + r] * w;
            }
            CKT[b * CKK + j] = a0;
            CKS[b * CKK + j] = a1;
        }
        __syncthreads();
    } else {
        for (int cidx = (blk - 450) * 256 + t; cidx < 22500; cidx += 62 * 256) {
            int uv = cidx / 2500;
            int r = cidx % 2500;          // b*100+p
            int src = (r / 100) * 900 + uv * 100 + (r % 100);
            SKsT[cidx] = SKS[src] + SKS[22500 + src];
        }
    }
    GSYNC(5);

    // ---- Ph6: task kernel assemble ----
    for (int idx = blk * 256 + t; idx < 576000; idx += NBLK * 256) {
        int uv = idx / 64000;
        int rem = idx % 64000;
        int c = rem / 100, p = rem % 100;
        float acc = 0.f;
#pragma unroll
        for (int b = 0; b < NBS; ++b)
            acc += CKT[b * CKK + c * 9 + uv] *
                   (SKT[b * 900 + uv * 100 + p] + SKT[22500 + b * 900 + uv * 100 + p]);
        TKT[idx] = acc * 0.04f;
    }
}

// Merged involutions, verbatim from the harness-verified round-0 kernel.
__global__ __launch_bounds__(256) void involutions(
        const float* __restrict__ sf, const float* __restrict__ qf,
        const float* __restrict__ taskT, const float* __restrict__ cks,
        const float* __restrict__ sksT, float* __restrict__ out) {
    int idx = blockIdx.x * 256 + threadIdx.x;     // max 6.4M
    bool support = idx < NBS * SF_B;
    int b, c, p;
    const float* x;
    if (support) {
        b = idx / SF_B; int rem = idx % SF_B; c = rem / 100; p = rem % 100;
        x = sf + b * SF_B + c * 100;
    } else {
        int qidx = idx - NBS * SF_B;
        b = qidx / SF_B; int rem = qidx % SF_B; c = rem / 100; p = rem % 100;
        x = qf + b * SF_B + c * 100;
    }
    int i = p / 10, j = p % 10;
    float acc = 0.f;
#pragma unroll
    for (int u = 0; u < 3; ++u) {
        int ii = i + u - 1;
        float mrow = ((unsigned)ii < 10u) ? 1.f : 0.f;
        int ci = min(max(ii, 0), 9);
#pragma unroll
        for (int v = 0; v < 3; ++v) {
            int jj = j + v - 1;
            float m = ((unsigned)jj < 10u) ? mrow : 0.f;
            int cj = min(max(jj, 0), 9);
            float xv = x[ci * 10 + cj] * m;     // clamped addr, masked value
            int uv = u * 3 + v;
            float w = taskT[uv * 64000 + c * 100 + p];
            if (support)
                w *= cks[b * CKK + c * 9 + uv] * sksT[uv * 2500 + b * 100 + p];
            acc += w * xv;
        }
    }
    out[idx] = acc;
}

extern "C" void kernel_launch(void* const* d_in, const int* in_sizes, int n_in,
                              void* d_out, int out_size, void* d_ws, size_t ws_size,
                              hipStream_t stream) {
    const float* sf  = (const float*)d_in[0];
    const float* qf  = (const float*)d_in[1];
    const float* Wc1 = (const float*)d_in[2];
    const float* bc1 = (const float*)d_in[3];
    const float* Wc2 = (const float*)d_in[4];
    const float* bc2 = (const float*)d_in[5];
    const float* Wc3 = (const float*)d_in[6];
    const float* bc3 = (const float*)d_in[7];
    const float* Wc4 = (const float*)d_in[8];
    const float* bc4 = (const float*)d_in[9];
    const float* W1 = (const float*)d_in[10];
    const float* b1 = (const float*)d_in[11];
    const float* W2 = (const float*)d_in[12];
    const float* b2 = (const float*)d_in[13];
    const float* Ws = (const float*)d_in[14];
    const float* bs = (const float*)d_in[15];
    float* out = (float*)d_out;
    float* ws = (float*)d_ws;

    // zero the per-block barrier flag lines (6 ids x 2 x 512 x 64 B = 384 KB)
    hipMemsetAsync((char*)d_ws + OFF_BAR * sizeof(float), 0, 393216, stream);

    mega_front<<<NBLK, 256, 0, stream>>>(sf, Wc1, bc1, Wc2, bc2, Wc3, bc3,
                                         Wc4, bc4, W1, b1, W2, b2, Ws, bs, ws);

    involutions<<<25000, 256, 0, stream>>>(sf, qf, ws + OFF_TASKT, ws + OFF_CKS,
                                           ws + OFF_SKSCT, out);
}